// Round 8
// baseline (220.883 us; speedup 1.0000x reference)
//
#include <hip/hip_runtime.h>
#include <math.h>

typedef float v2f __attribute__((ext_vector_type(2)));
typedef float v4f __attribute__((ext_vector_type(4)));

#define LT(i,j) ((i)*((i)+1)/2 + (j))

// reflect index into [0,512)
__device__ __forceinline__ int reflect512(int i) {
  int a = (i < 0) ? -i : i;
  int b = 1022 - a;
  return (a < b) ? a : b;
}

// ---- halo'd CHUNK-PLANAR buffer, halo=4, reflected.
// Each pixel is 12 floats = three 16B chunks:
//   chunk0=[x0x1x2x3] chunk1=[x4x5y0y1] chunk2=[y2y3y4y5]
// zb split into 3 planes of chunks: addr(b,r,c,p) = zb + p*PSTR + ((b*HB+r)*HB+c)*4
constexpr int HB   = 520;               // 512 + 2*4 halo
constexpr int RSP  = HB * 4;            // floats per halo row within a plane
constexpr int PSTR = 2 * HB * HB * 4;   // floats per plane (both batches)

// Monotonic grid-barrier ticket counter. Never reset; target derived from
// ticket/512 so it works whether or not the module global survives replays.
__device__ unsigned int g_bar = 0;

// One prep unit = (chunk-plane p, batch b, halo row hr, 4-col group q):
// 4 channel loads + 4 contiguous dwordx4 stores.
__device__ __forceinline__ void prep_unit(int idx,
                                          const float* __restrict__ xg,
                                          const float* __restrict__ yg,
                                          float* __restrict__ zb) {
  constexpr int H = 512, W = 512, HW = H * W;
  constexpr int WQ  = HB / 4;            // 130 groups of 4 columns
  constexpr int PER = 2 * HB * WQ;       // units per chunk-plane
  const int p  = idx / PER;              // chunk plane 0..2
  int r        = idx - p * PER;
  const int b  = r / (HB * WQ);
  r           -= b * (HB * WQ);
  const int hr = r / WQ;
  const int q  = r - hr * WQ;
  const int h  = reflect512(hr - 4);
  const int w0 = q * 4 - 4;              // first source col (halo - 4)

  float v[4][4];                         // [chan][px]
  #pragma unroll
  for (int c = 0; c < 4; ++c) {
    const int ch = 4 * p + c;
    const float* src = (ch < 6 ? xg : yg)
                     + (size_t)b * 6 * HW + (size_t)(ch % 6) * HW
                     + (size_t)h * W;
    if (w0 >= 0 && w0 + 3 < W) {
      const v4f t = *(const v4f*)(src + w0);
      #pragma unroll
      for (int j = 0; j < 4; ++j) v[c][j] = t[j];
    } else {
      #pragma unroll
      for (int j = 0; j < 4; ++j) v[c][j] = src[reflect512(w0 + j)];
    }
  }

  float* o = zb + (size_t)p * PSTR + ((size_t)(b * HB + hr) * HB + q * 4) * 4;
  #pragma unroll
  for (int j = 0; j < 4; ++j) {
    v4f t = {v[0][j], v[1][j], v[2][j], v[3][j]};
    *(v4f*)(o + j * 4) = t;
  }
}

// Gram entry g[a][b] (a>=b) from the 2x2-block pk accumulators.
__device__ __forceinline__ float gget(const v2f* accd, const v2f* accs,
                                      int a, int b) {
  const int t = LT(a >> 1, b >> 1);
  if (((a & 1) == 0) && ((b & 1) == 0)) return accd[t].x;
  if (((a & 1) == 1) && ((b & 1) == 1)) return accd[t].y;
  if ((a & 1) == 0) return accs[t].x;
  return accs[t].y;
}

// Packed-lower SPD 6x6 -> packed-lower L^{-1} in place. Divide/sqrt-free.
__device__ __forceinline__ void cholinv6(float* a) {
  #pragma unroll
  for (int j = 0; j < 6; ++j) {
    float d = a[LT(j,j)];
    #pragma unroll
    for (int p = 0; p < j; ++p) d -= a[LT(j,p)] * a[LT(j,p)];
    const float rd = __builtin_amdgcn_rsqf(d);
    a[LT(j,j)] = rd;
    #pragma unroll
    for (int i = j + 1; i < 6; ++i) {
      float s = a[LT(i,j)];
      #pragma unroll
      for (int p = 0; p < j; ++p) s -= a[LT(i,p)] * a[LT(j,p)];
      a[LT(i,j)] = s * rd;
    }
  }
  #pragma unroll
  for (int j = 0; j < 6; ++j) {
    #pragma unroll
    for (int i = j + 1; i < 6; ++i) {
      float s = 0.0f;
      #pragma unroll
      for (int p = j; p < i; ++p) s += a[LT(i,p)] * a[LT(p,j)];
      a[LT(i,j)] = -s * a[LT(i,i)];
    }
  }
}

// +/- one pixel's products into the Gram accumulators.
// p points at the pixel's chunk in plane 0; other chunks at +PSTR/+2*PSTR.
template <bool ADD>
__device__ __forceinline__ void px_acc(const float* __restrict__ p,
                                       v2f* zs, v2f* accd, v2f* accs) {
  const v4f l0 = *(const v4f*)(p + 0 * PSTR);
  const v4f l1 = *(const v4f*)(p + 1 * PSTR);
  const v4f l2 = *(const v4f*)(p + 2 * PSTR);
  v2f z[6];
  z[0] = l0.lo; z[1] = l0.hi;
  z[2] = l1.lo; z[3] = l1.hi;
  z[4] = l2.lo; z[5] = l2.hi;
  #pragma unroll
  for (int q = 0; q < 6; ++q) zs[q] = ADD ? (zs[q] + z[q]) : (zs[q] - z[q]);
  int t = 0;
  #pragma unroll
  for (int Kp = 0; Kp < 6; ++Kp) {
    #pragma unroll
    for (int Pp = 0; Pp <= Kp; ++Pp) {
      const v2f c  = z[Pp];
      const v2f cs = __builtin_shufflevector(c, c, 1, 0);
      const v2f a  = ADD ? z[Kp] : -z[Kp];
      accd[t] = __builtin_elementwise_fma(a, c,  accd[t]);
      accs[t] = __builtin_elementwise_fma(a, cs, accs[t]);
      ++t;
    }
  }
}

// +/- one window row's K pixels; p points at the row's leftmost pixel chunk
// in plane 0. Per-dx offsets are +16B immediates within each plane.
template <int K, bool ADD>
__device__ __forceinline__ void row_acc_g(const float* __restrict__ p,
                                          v2f* zs, v2f* accd, v2f* accs) {
  #pragma unroll
  for (int dx = 0; dx < K; ++dx) px_acc<ADD>(p + dx * 4, zs, accd, accs);
}

// ---- emit, split in two for software pipelining ----
template <int K>
__device__ __forceinline__ void extract_emit(const v2f* zs, const v2f* accd,
                                             const v2f* accs,
                                             float* ax, float* ay, float* cxy) {
  constexpr float inv_n = 1.0f / (K * K);
  float mx[6], my[6];
  #pragma unroll
  for (int i = 0; i < 6; ++i) {
    mx[i] = ((i & 1) ? zs[i >> 1].y : zs[i >> 1].x) * inv_n;
    my[i] = ((i & 1) ? zs[3 + (i >> 1)].y : zs[3 + (i >> 1)].x) * inv_n;
  }
  {
    int t = 0;
    #pragma unroll
    for (int i = 0; i < 6; ++i)
      #pragma unroll
      for (int j = 0; j <= i; ++j) {
        const float e = (i == j) ? 1e-6f : 0.0f;
        ax[t] = gget(accd, accs, i, j) * inv_n - mx[i] * mx[j] + e;
        ay[t] = gget(accd, accs, 6 + i, 6 + j) * inv_n - my[i] * my[j] + e;
        ++t;
      }
  }
  #pragma unroll
  for (int i = 0; i < 6; ++i)
    #pragma unroll
    for (int j = 0; j < 6; ++j)
      cxy[i * 6 + j] = fmaf(-mx[i], my[j], gget(accd, accs, 6 + j, i) * inv_n);
}

__device__ __forceinline__ float finish_sim(float* ax, float* ay,
                                            const float* cxy) {
  cholinv6(ax);
  cholinv6(ay);
  float sim = 0.0f;
  #pragma unroll
  for (int i = 0; i < 6; ++i) {
    float di = 0.0f;
    #pragma unroll
    for (int j = 0; j <= i; ++j) {
      float inner = 0.0f;
      #pragma unroll
      for (int k = i; k < 6; ++k) inner += cxy[j * 6 + k] * ay[LT(k, i)];
      di += ax[LT(i, j)] * inner;
    }
    sim += fabsf(di);
  }
  return sim * (1.0f / 6.0f);
}

// One radius+batch per z. 16 tx x 16 strips, V=8 outputs per strip.
template <int R, int V>
__device__ __forceinline__ void run(const float* __restrict__ zb,
                                    float* __restrict__ out, int b, int ri) {
  constexpr int K = 2 * R + 1;
  constexpr int H = 512, W = 512;

  const int h0 = blockIdx.y * (16 * V);
  const int w0 = blockIdx.x * 16;
  const int tx = threadIdx.x & 15;
  const int g  = threadIdx.x >> 4;
  const int hbase = h0 + g * V;
  const int wc = w0 + tx;

  const float* base = zb +
      ((size_t)(b * HB + (hbase + 4 - R)) * HB + (wc + 4 - R)) * 4;

  v2f zs[6]    = {};
  v2f accd[21] = {};
  v2f accs[21] = {};

  #pragma unroll 1
  for (int dy = 0; dy < K; ++dy)
    row_acc_g<K, true>(base + dy * RSP, zs, accd, accs);

  float ax[21], ay[21], cxy[36];
  extract_emit<K>(zs, accd, accs, ax, ay, cxy);   // output row hbase (s=0)

  #pragma unroll 1
  for (int s = 1; s < V; ++s) {
    row_acc_g<K, true >(base + (s + 2 * R) * RSP, zs, accd, accs);  // entering
    row_acc_g<K, false>(base + (s - 1)     * RSP, zs, accd, accs);  // leaving
    out[((size_t)((b * H + hbase + s - 1) * W + wc)) * 2 + ri] =
        finish_sim(ax, ay, cxy);
    extract_emit<K>(zs, accd, accs, ax, ay, cxy);  // output row hbase+s
  }
  out[((size_t)((b * H + hbase + V - 1) * W + wc)) * 2 + ri] =
      finish_sim(ax, ay, cxy);
}

// Fused prep + grid-barrier + cca. Grid = 512 blocks x 256 thr with
// __launch_bounds__(256,2): VGPR<=128, LDS=0 -> 2 blocks/CU x 256 CU = 512,
// so ALL blocks are co-resident and the spin barrier cannot deadlock.
// Barrier: monotonic tickets; replay n's 512 arrivals are stream-ordered, so
// target=(ticket/512+1)*512 is exact whether or not g_bar was reset.
__global__ __launch_bounds__(256, 2)
void cca_fused(const float* __restrict__ xg, const float* __restrict__ yg,
               float* __restrict__ zb, float* __restrict__ out) {
  constexpr int WQ    = HB / 4;
  constexpr int NPREP = 3 * 2 * HB * WQ;      // 405,600 prep units
  constexpr int NTHR  = 512 * 256;

  // ---- phase 1: grid-strided prep (~3.1 units/thread) ----
  const int bid = ((int)blockIdx.z * 4 + (int)blockIdx.y) * 32 + (int)blockIdx.x;
  for (int idx = bid * 256 + (int)threadIdx.x; idx < NPREP; idx += NTHR)
    prep_unit(idx, xg, yg, zb);

  // ---- grid barrier: release zb writes, arrive, spin, acquire ----
  __syncthreads();
  if (threadIdx.x == 0) {
    __threadfence();   // device-scope release: push zb writes past L2
    const unsigned my = __hip_atomic_fetch_add(&g_bar, 1u, __ATOMIC_ACQ_REL,
                                               __HIP_MEMORY_SCOPE_AGENT);
    const unsigned target = (my / 512u + 1u) * 512u;
    while (__hip_atomic_load(&g_bar, __ATOMIC_ACQUIRE,
                             __HIP_MEMORY_SCOPE_AGENT) < target)
      __builtin_amdgcn_s_sleep(2);
    __threadfence();   // device-scope acquire: invalidate stale L1/L2
  }
  __syncthreads();

  // ---- phase 2: cca (unchanged) ----
  const int z = blockIdx.z;
  if (z < 2) run<2, 8>(zb, out, z, 0);
  else       run<4, 8>(zb, out, z - 2, 1);
}

extern "C" void kernel_launch(void* const* d_in, const int* in_sizes, int n_in,
                              void* d_out, int out_size, void* d_ws, size_t ws_size,
                              hipStream_t stream) {
  const float* x = (const float*)d_in[0];
  const float* y = (const float*)d_in[1];
  float* out = (float*)d_out;
  float* zb  = (float*)d_ws;   // needs 3*PSTR*4 B = 25.96 MB

  dim3 grid(512 / 16, 512 / (16 * 8), 4);   // 32 x 4 x 4 = 512 blocks
  cca_fused<<<grid, dim3(256), 0, stream>>>(x, y, zb, out);
}

// Round 9
// 213.033 us; speedup vs baseline: 1.0368x; 1.0368x over previous
//
#include <hip/hip_runtime.h>
#include <math.h>

typedef float v2f __attribute__((ext_vector_type(2)));
typedef float v4f __attribute__((ext_vector_type(4)));

#define LT(i,j) ((i)*((i)+1)/2 + (j))

// reflect index into [0,512)
__device__ __forceinline__ int reflect512(int i) {
  int a = (i < 0) ? -i : i;
  int b = 1022 - a;
  return (a < b) ? a : b;
}

// ---- halo'd CHUNK-PLANAR buffer, halo=4, reflected.
// Each pixel is 12 floats = three 16B chunks:
//   chunk0=[x0x1x2x3] chunk1=[x4x5y0y1] chunk2=[y2y3y4y5]
// zb split into 3 planes of chunks: addr(b,r,c,p) = zb + p*PSTR + ((b*HB+r)*HB+c)*4
constexpr int HB   = 520;               // 512 + 2*4 halo
constexpr int RSP  = HB * 4;            // floats per halo row within a plane
constexpr int PSTR = 2 * HB * HB * 4;   // floats per plane (both batches)

// Monotonic grid-barrier ticket counter (never reset; replay-safe).
__device__ unsigned int g_bar = 0;

// Load one prep unit's 16 floats into v and return its zb store pointer.
// Unit = (chunk-plane p, batch b, halo row hr, 4-col group q).
__device__ __forceinline__ float* prep_load(int idx,
    const float* __restrict__ xg, const float* __restrict__ yg,
    float* __restrict__ zb, float v[4][4]) {
  constexpr int H = 512, W = 512, HW = H * W;
  constexpr int WQ  = HB / 4;            // 130 groups of 4 columns
  constexpr int PER = 2 * HB * WQ;       // units per chunk-plane
  const int p  = idx / PER;              // chunk plane 0..2
  int r        = idx - p * PER;
  const int b  = r / (HB * WQ);
  r           -= b * (HB * WQ);
  const int hr = r / WQ;
  const int q  = r - hr * WQ;
  const int h  = reflect512(hr - 4);
  const int w0 = q * 4 - 4;              // first source col (halo - 4)

  #pragma unroll
  for (int c = 0; c < 4; ++c) {
    const int ch = 4 * p + c;
    const float* src = (ch < 6 ? xg : yg)
                     + (size_t)b * 6 * HW + (size_t)(ch % 6) * HW
                     + (size_t)h * W;
    if (w0 >= 0 && w0 + 3 < W) {
      const v4f t = *(const v4f*)(src + w0);
      #pragma unroll
      for (int j = 0; j < 4; ++j) v[c][j] = t[j];
    } else {
      #pragma unroll
      for (int j = 0; j < 4; ++j) v[c][j] = src[reflect512(w0 + j)];
    }
  }
  return zb + (size_t)p * PSTR + ((size_t)(b * HB + hr) * HB + q * 4) * 4;
}

__device__ __forceinline__ void prep_store(float* __restrict__ o,
                                           const float v[4][4]) {
  #pragma unroll
  for (int j = 0; j < 4; ++j) {
    v4f t = {v[0][j], v[1][j], v[2][j], v[3][j]};
    *(v4f*)(o + j * 4) = t;
  }
}

// Gram entry g[a][b] (a>=b) from the 2x2-block pk accumulators.
__device__ __forceinline__ float gget(const v2f* accd, const v2f* accs,
                                      int a, int b) {
  const int t = LT(a >> 1, b >> 1);
  if (((a & 1) == 0) && ((b & 1) == 0)) return accd[t].x;
  if (((a & 1) == 1) && ((b & 1) == 1)) return accd[t].y;
  if ((a & 1) == 0) return accs[t].x;
  return accs[t].y;
}

// Packed-lower SPD 6x6 -> packed-lower L^{-1} in place. Divide/sqrt-free.
__device__ __forceinline__ void cholinv6(float* a) {
  #pragma unroll
  for (int j = 0; j < 6; ++j) {
    float d = a[LT(j,j)];
    #pragma unroll
    for (int p = 0; p < j; ++p) d -= a[LT(j,p)] * a[LT(j,p)];
    const float rd = __builtin_amdgcn_rsqf(d);
    a[LT(j,j)] = rd;
    #pragma unroll
    for (int i = j + 1; i < 6; ++i) {
      float s = a[LT(i,j)];
      #pragma unroll
      for (int p = 0; p < j; ++p) s -= a[LT(i,p)] * a[LT(j,p)];
      a[LT(i,j)] = s * rd;
    }
  }
  #pragma unroll
  for (int j = 0; j < 6; ++j) {
    #pragma unroll
    for (int i = j + 1; i < 6; ++i) {
      float s = 0.0f;
      #pragma unroll
      for (int p = j; p < i; ++p) s += a[LT(i,p)] * a[LT(p,j)];
      a[LT(i,j)] = -s * a[LT(i,i)];
    }
  }
}

// +/- one pixel's products into the Gram accumulators.
// p points at the pixel's chunk in plane 0; other chunks at +PSTR/+2*PSTR.
template <bool ADD>
__device__ __forceinline__ void px_acc(const float* __restrict__ p,
                                       v2f* zs, v2f* accd, v2f* accs) {
  const v4f l0 = *(const v4f*)(p + 0 * PSTR);
  const v4f l1 = *(const v4f*)(p + 1 * PSTR);
  const v4f l2 = *(const v4f*)(p + 2 * PSTR);
  v2f z[6];
  z[0] = l0.lo; z[1] = l0.hi;
  z[2] = l1.lo; z[3] = l1.hi;
  z[4] = l2.lo; z[5] = l2.hi;
  #pragma unroll
  for (int q = 0; q < 6; ++q) zs[q] = ADD ? (zs[q] + z[q]) : (zs[q] - z[q]);
  int t = 0;
  #pragma unroll
  for (int Kp = 0; Kp < 6; ++Kp) {
    #pragma unroll
    for (int Pp = 0; Pp <= Kp; ++Pp) {
      const v2f c  = z[Pp];
      const v2f cs = __builtin_shufflevector(c, c, 1, 0);
      const v2f a  = ADD ? z[Kp] : -z[Kp];
      accd[t] = __builtin_elementwise_fma(a, c,  accd[t]);
      accs[t] = __builtin_elementwise_fma(a, cs, accs[t]);
      ++t;
    }
  }
}

// +/- one window row's K pixels; p points at the row's leftmost pixel chunk
// in plane 0. Per-dx offsets are +16B immediates within each plane.
template <int K, bool ADD>
__device__ __forceinline__ void row_acc_g(const float* __restrict__ p,
                                          v2f* zs, v2f* accd, v2f* accs) {
  #pragma unroll
  for (int dx = 0; dx < K; ++dx) px_acc<ADD>(p + dx * 4, zs, accd, accs);
}

// ---- emit, split in two for software pipelining ----
template <int K>
__device__ __forceinline__ void extract_emit(const v2f* zs, const v2f* accd,
                                             const v2f* accs,
                                             float* ax, float* ay, float* cxy) {
  constexpr float inv_n = 1.0f / (K * K);
  float mx[6], my[6];
  #pragma unroll
  for (int i = 0; i < 6; ++i) {
    mx[i] = ((i & 1) ? zs[i >> 1].y : zs[i >> 1].x) * inv_n;
    my[i] = ((i & 1) ? zs[3 + (i >> 1)].y : zs[3 + (i >> 1)].x) * inv_n;
  }
  {
    int t = 0;
    #pragma unroll
    for (int i = 0; i < 6; ++i)
      #pragma unroll
      for (int j = 0; j <= i; ++j) {
        const float e = (i == j) ? 1e-6f : 0.0f;
        ax[t] = gget(accd, accs, i, j) * inv_n - mx[i] * mx[j] + e;
        ay[t] = gget(accd, accs, 6 + i, 6 + j) * inv_n - my[i] * my[j] + e;
        ++t;
      }
  }
  #pragma unroll
  for (int i = 0; i < 6; ++i)
    #pragma unroll
    for (int j = 0; j < 6; ++j)
      cxy[i * 6 + j] = fmaf(-mx[i], my[j], gget(accd, accs, 6 + j, i) * inv_n);
}

__device__ __forceinline__ float finish_sim(float* ax, float* ay,
                                            const float* cxy) {
  cholinv6(ax);
  cholinv6(ay);
  float sim = 0.0f;
  #pragma unroll
  for (int i = 0; i < 6; ++i) {
    float di = 0.0f;
    #pragma unroll
    for (int j = 0; j <= i; ++j) {
      float inner = 0.0f;
      #pragma unroll
      for (int k = i; k < 6; ++k) inner += cxy[j * 6 + k] * ay[LT(k, i)];
      di += ax[LT(i, j)] * inner;
    }
    sim += fabsf(di);
  }
  return sim * (1.0f / 6.0f);
}

// One radius+batch per z. 16 tx x 16 strips, V=8 outputs per strip.
template <int R, int V>
__device__ __forceinline__ void run(const float* __restrict__ zb,
                                    float* __restrict__ out, int b, int ri) {
  constexpr int K = 2 * R + 1;
  constexpr int H = 512, W = 512;

  const int h0 = blockIdx.y * (16 * V);
  const int w0 = blockIdx.x * 16;
  const int tx = threadIdx.x & 15;
  const int g  = threadIdx.x >> 4;
  const int hbase = h0 + g * V;
  const int wc = w0 + tx;

  const float* base = zb +
      ((size_t)(b * HB + (hbase + 4 - R)) * HB + (wc + 4 - R)) * 4;

  v2f zs[6]    = {};
  v2f accd[21] = {};
  v2f accs[21] = {};

  #pragma unroll 1
  for (int dy = 0; dy < K; ++dy)
    row_acc_g<K, true>(base + dy * RSP, zs, accd, accs);

  float ax[21], ay[21], cxy[36];
  extract_emit<K>(zs, accd, accs, ax, ay, cxy);   // output row hbase (s=0)

  #pragma unroll 1
  for (int s = 1; s < V; ++s) {
    row_acc_g<K, true >(base + (s + 2 * R) * RSP, zs, accd, accs);  // entering
    row_acc_g<K, false>(base + (s - 1)     * RSP, zs, accd, accs);  // leaving
    out[((size_t)((b * H + hbase + s - 1) * W + wc)) * 2 + ri] =
        finish_sim(ax, ay, cxy);
    extract_emit<K>(zs, accd, accs, ax, ay, cxy);  // output row hbase+s
  }
  out[((size_t)((b * H + hbase + V - 1) * W + wc)) * 2 + ri] =
      finish_sim(ax, ay, cxy);
}

// Fused prep + grid-barrier + cca. 512 blocks x 256 thr, launch_bounds(256,2)
// -> VGPR<=128, LDS=0 -> 2 blocks/CU x 256 CU = 512: all blocks co-resident,
// spin barrier cannot deadlock (empirically held in round 8).
// Round-9 fixes vs round 8:
//  - prep: units batched 2-deep, loads of both units issued before stores
//    (2x MLP at the same wave count; r8 serialized unit-by-unit).
//  - spin: s_sleep(32) (16x fewer polls AND 16x fewer acquire-invalidates;
//    r8 polled with buffer_inv every ~0.2us x 512 spinners).
//  - arrival fetch_add RELAXED (explicit threadfences already order it);
//    spin load stays ACQUIRE — a relaxed agent load may legally be served
//    by the local non-coherent XCD L2 and never observe remote arrivals.
__global__ __launch_bounds__(256, 2)
void cca_fused(const float* __restrict__ xg, const float* __restrict__ yg,
               float* __restrict__ zb, float* __restrict__ out) {
  constexpr int WQ    = HB / 4;
  constexpr int NPREP = 3 * 2 * HB * WQ;      // 405,600 prep units
  constexpr int NTHR  = 512 * 256;            // 131,072 threads

  // ---- phase 1: prep, 2-deep unit batches (~3.1 units/thread) ----
  const int bid = ((int)blockIdx.z * 4 + (int)blockIdx.y) * 32 + (int)blockIdx.x;
  const int t0  = bid * 256 + (int)threadIdx.x;
  #pragma unroll
  for (int uu = 0; uu < 4; uu += 2) {
    const int ia = t0 + uu * NTHR;
    const int ib = t0 + (uu + 1) * NTHR;
    float va[4][4], vb[4][4];
    float* oa = (ia < NPREP) ? prep_load(ia, xg, yg, zb, va) : nullptr;
    float* ob = (ib < NPREP) ? prep_load(ib, xg, yg, zb, vb) : nullptr;
    if (oa) prep_store(oa, va);
    if (ob) prep_store(ob, vb);
  }

  // ---- grid barrier ----
  __syncthreads();
  if (threadIdx.x == 0) {
    __threadfence();   // release: drain + push zb writes past local L2
    const unsigned my = __hip_atomic_fetch_add(&g_bar, 1u, __ATOMIC_RELAXED,
                                               __HIP_MEMORY_SCOPE_AGENT);
    const unsigned target = (my / 512u + 1u) * 512u;
    while (__hip_atomic_load(&g_bar, __ATOMIC_ACQUIRE,
                             __HIP_MEMORY_SCOPE_AGENT) < target)
      __builtin_amdgcn_s_sleep(32);
    __threadfence();   // acquire: invalidate stale cached zb
  }
  __syncthreads();

  // ---- phase 2: cca (unchanged) ----
  const int z = blockIdx.z;
  if (z < 2) run<2, 8>(zb, out, z, 0);
  else       run<4, 8>(zb, out, z - 2, 1);
}

extern "C" void kernel_launch(void* const* d_in, const int* in_sizes, int n_in,
                              void* d_out, int out_size, void* d_ws, size_t ws_size,
                              hipStream_t stream) {
  const float* x = (const float*)d_in[0];
  const float* y = (const float*)d_in[1];
  float* out = (float*)d_out;
  float* zb  = (float*)d_ws;   // needs 3*PSTR*4 B = 25.96 MB

  dim3 grid(512 / 16, 512 / (16 * 8), 4);   // 32 x 4 x 4 = 512 blocks
  cca_fused<<<grid, dim3(256), 0, stream>>>(x, y, zb, out);
}

// Round 10
// 145.985 us; speedup vs baseline: 1.5131x; 1.4593x over previous
//
#include <hip/hip_runtime.h>
#include <math.h>

typedef float v2f __attribute__((ext_vector_type(2)));
typedef float v4f __attribute__((ext_vector_type(4)));

#define LT(i,j) ((i)*((i)+1)/2 + (j))

// reflect index into [0,512)
__device__ __forceinline__ int reflect512(int i) {
  int a = (i < 0) ? -i : i;
  int b = 1022 - a;
  return (a < b) ? a : b;
}

// ---- halo'd CHUNK-PLANAR buffer, halo=4, reflected.
// Each pixel is 12 floats = three 16B chunks:
//   chunk0=[x0x1x2x3] chunk1=[x4x5y0y1] chunk2=[y2y3y4y5]
// zb split into 3 planes of chunks: addr(b,r,c,p) = zb + p*PSTR + ((b*HB+r)*HB+c)*4
constexpr int HB   = 520;               // 512 + 2*4 halo
constexpr int RSP  = HB * 4;            // floats per halo row within a plane
constexpr int PSTR = 2 * HB * HB * 4;   // floats per plane (both batches)

// prep: one thread per (chunk-plane p, batch b, halo row hr, 4-col group q).
// 405,600 threads / 1585 blocks; 4 channel loads + 4 contiguous dwordx4 stores.
__global__ __launch_bounds__(256)
void prep_planar_t(const float* __restrict__ xg, const float* __restrict__ yg,
                   float* __restrict__ zb) {
  constexpr int H = 512, W = 512, HW = H * W;
  constexpr int WQ  = HB / 4;            // 130 groups of 4 columns
  constexpr int PER = 2 * HB * WQ;       // threads per chunk-plane (135,200)
  const int idx = blockIdx.x * 256 + threadIdx.x;
  if (idx >= 3 * PER) return;
  const int p  = idx / PER;              // chunk plane 0..2 (wave-uniform)
  int r        = idx - p * PER;
  const int b  = r / (HB * WQ);
  r           -= b * (HB * WQ);
  const int hr = r / WQ;
  const int q  = r - hr * WQ;
  const int h  = reflect512(hr - 4);
  const int w0 = q * 4 - 4;              // first source col (halo - 4)

  float v[4][4];                         // [chan][px]
  #pragma unroll
  for (int c = 0; c < 4; ++c) {
    const int ch = 4 * p + c;
    const float* src = (ch < 6 ? xg : yg)
                     + (size_t)b * 6 * HW + (size_t)(ch % 6) * HW
                     + (size_t)h * W;
    if (w0 >= 0 && w0 + 3 < W) {
      const v4f t = *(const v4f*)(src + w0);
      #pragma unroll
      for (int j = 0; j < 4; ++j) v[c][j] = t[j];
    } else {
      #pragma unroll
      for (int j = 0; j < 4; ++j) v[c][j] = src[reflect512(w0 + j)];
    }
  }

  float* o = zb + (size_t)p * PSTR + ((size_t)(b * HB + hr) * HB + q * 4) * 4;
  #pragma unroll
  for (int j = 0; j < 4; ++j) {
    v4f t = {v[0][j], v[1][j], v[2][j], v[3][j]};
    *(v4f*)(o + j * 4) = t;
  }
}

// Gram entry g[a][b] (a>=b) from the 2x2-block pk accumulators.
__device__ __forceinline__ float gget(const v2f* accd, const v2f* accs,
                                      int a, int b) {
  const int t = LT(a >> 1, b >> 1);
  if (((a & 1) == 0) && ((b & 1) == 0)) return accd[t].x;
  if (((a & 1) == 1) && ((b & 1) == 1)) return accd[t].y;
  if ((a & 1) == 0) return accs[t].x;
  return accs[t].y;
}

// Packed-lower SPD 6x6 -> packed-lower L^{-1} in place. Divide/sqrt-free.
__device__ __forceinline__ void cholinv6(float* a) {
  #pragma unroll
  for (int j = 0; j < 6; ++j) {
    float d = a[LT(j,j)];
    #pragma unroll
    for (int p = 0; p < j; ++p) d -= a[LT(j,p)] * a[LT(j,p)];
    const float rd = __builtin_amdgcn_rsqf(d);
    a[LT(j,j)] = rd;
    #pragma unroll
    for (int i = j + 1; i < 6; ++i) {
      float s = a[LT(i,j)];
      #pragma unroll
      for (int p = 0; p < j; ++p) s -= a[LT(i,p)] * a[LT(j,p)];
      a[LT(i,j)] = s * rd;
    }
  }
  #pragma unroll
  for (int j = 0; j < 6; ++j) {
    #pragma unroll
    for (int i = j + 1; i < 6; ++i) {
      float s = 0.0f;
      #pragma unroll
      for (int p = j; p < i; ++p) s += a[LT(i,p)] * a[LT(p,j)];
      a[LT(i,j)] = -s * a[LT(i,i)];
    }
  }
}

// +/- one pixel's products into the Gram accumulators.
// p points at the pixel's chunk in plane 0; other chunks at +PSTR/+2*PSTR.
template <bool ADD>
__device__ __forceinline__ void px_acc(const float* __restrict__ p,
                                       v2f* zs, v2f* accd, v2f* accs) {
  const v4f l0 = *(const v4f*)(p + 0 * PSTR);
  const v4f l1 = *(const v4f*)(p + 1 * PSTR);
  const v4f l2 = *(const v4f*)(p + 2 * PSTR);
  v2f z[6];
  z[0] = l0.lo; z[1] = l0.hi;
  z[2] = l1.lo; z[3] = l1.hi;
  z[4] = l2.lo; z[5] = l2.hi;
  #pragma unroll
  for (int q = 0; q < 6; ++q) zs[q] = ADD ? (zs[q] + z[q]) : (zs[q] - z[q]);
  int t = 0;
  #pragma unroll
  for (int Kp = 0; Kp < 6; ++Kp) {
    #pragma unroll
    for (int Pp = 0; Pp <= Kp; ++Pp) {
      const v2f c  = z[Pp];
      const v2f cs = __builtin_shufflevector(c, c, 1, 0);
      const v2f a  = ADD ? z[Kp] : -z[Kp];
      accd[t] = __builtin_elementwise_fma(a, c,  accd[t]);
      accs[t] = __builtin_elementwise_fma(a, cs, accs[t]);
      ++t;
    }
  }
}

// Warm-up path: one row, all adds.
template <int K>
__device__ __forceinline__ void row_acc_g(const float* __restrict__ p,
                                          v2f* zs, v2f* accd, v2f* accs) {
  #pragma unroll
  for (int dx = 0; dx < K; ++dx) px_acc<true>(p + dx * 4, zs, accd, accs);
}

// Steady-state: ENTER row (+) and LEAVE row (-) interleaved pixel-by-pixel.
// Two independent load chains -> 6 loads per FMA window instead of 3, so the
// L1-cold leave-row loads (L2 latency: last touched K steps ago, evicted from
// the 32KB L1) overlap the enter-row FMAs instead of serializing behind them.
template <int K>
__device__ __forceinline__ void row_acc_pair(const float* __restrict__ pe,
                                             const float* __restrict__ pl,
                                             v2f* zs, v2f* accd, v2f* accs) {
  #pragma unroll
  for (int dx = 0; dx < K; ++dx) {
    px_acc<true >(pe + dx * 4, zs, accd, accs);
    px_acc<false>(pl + dx * 4, zs, accd, accs);
  }
}

// ---- emit, split in two for software pipelining ----
// extract: ALL reads of acc/zs happen here (cheap, load-free). After this the
// accumulators are dead to this output and may be updated for the next step.
template <int K>
__device__ __forceinline__ void extract_emit(const v2f* zs, const v2f* accd,
                                             const v2f* accs,
                                             float* ax, float* ay, float* cxy) {
  constexpr float inv_n = 1.0f / (K * K);
  float mx[6], my[6];
  #pragma unroll
  for (int i = 0; i < 6; ++i) {
    mx[i] = ((i & 1) ? zs[i >> 1].y : zs[i >> 1].x) * inv_n;
    my[i] = ((i & 1) ? zs[3 + (i >> 1)].y : zs[3 + (i >> 1)].x) * inv_n;
  }
  {
    int t = 0;
    #pragma unroll
    for (int i = 0; i < 6; ++i)
      #pragma unroll
      for (int j = 0; j <= i; ++j) {
        const float e = (i == j) ? 1e-6f : 0.0f;
        ax[t] = gget(accd, accs, i, j) * inv_n - mx[i] * mx[j] + e;
        ay[t] = gget(accd, accs, 6 + i, 6 + j) * inv_n - my[i] * my[j] + e;
        ++t;
      }
  }
  #pragma unroll
  for (int i = 0; i < 6; ++i)
    #pragma unroll
    for (int j = 0; j < 6; ++j)
      cxy[i * 6 + j] = fmaf(-mx[i], my[j], gget(accd, accs, 6 + j, i) * inv_n);
}

// finish: register-only serial math (2x cholinv + triangular solve + abs-sum).
__device__ __forceinline__ float finish_sim(float* ax, float* ay,
                                            const float* cxy) {
  cholinv6(ax);
  cholinv6(ay);
  float sim = 0.0f;
  #pragma unroll
  for (int i = 0; i < 6; ++i) {
    float di = 0.0f;
    #pragma unroll
    for (int j = 0; j <= i; ++j) {
      float inner = 0.0f;
      #pragma unroll
      for (int k = i; k < 6; ++k) inner += cxy[j * 6 + k] * ay[LT(k, i)];
      di += ax[LT(i, j)] * inner;
    }
    sim += fabsf(di);
  }
  return sim * (1.0f / 6.0f);
}

// One radius+batch per z. 16 tx x 16 strips, V=8 outputs per strip.
// Software-pipelined: iteration s issues step-s loads/FMAs BEFORE the serial
// cholesky of output s-1, so cache latency hides under the dependency chains.
template <int R, int V>
__device__ __forceinline__ void run(const float* __restrict__ zb,
                                    float* __restrict__ out, int b, int ri) {
  constexpr int K = 2 * R + 1;
  constexpr int H = 512, W = 512;

  const int h0 = blockIdx.y * (16 * V);
  const int w0 = blockIdx.x * 16;
  const int tx = threadIdx.x & 15;
  const int g  = threadIdx.x >> 4;
  const int hbase = h0 + g * V;
  const int wc = w0 + tx;

  // chunk of the top-left window pixel, in halo coords (plane 0)
  const float* base = zb +
      ((size_t)(b * HB + (hbase + 4 - R)) * HB + (wc + 4 - R)) * 4;

  v2f zs[6]    = {};
  v2f accd[21] = {};
  v2f accs[21] = {};

  #pragma unroll 1
  for (int dy = 0; dy < K; ++dy)
    row_acc_g<K>(base + dy * RSP, zs, accd, accs);

  float ax[21], ay[21], cxy[36];
  extract_emit<K>(zs, accd, accs, ax, ay, cxy);   // output row hbase (s=0)

  #pragma unroll 1
  for (int s = 1; s < V; ++s) {
    // step-s window update: interleaved enter(+)/leave(-) chains issue first...
    row_acc_pair<K>(base + (s + 2 * R) * RSP,   // entering row
                    base + (s - 1) * RSP,       // leaving row
                    zs, accd, accs);
    // ...then the serial math for output s-1 runs while loads are in flight.
    out[((size_t)((b * H + hbase + s - 1) * W + wc)) * 2 + ri] =
        finish_sim(ax, ay, cxy);
    extract_emit<K>(zs, accd, accs, ax, ay, cxy);  // output row hbase+s
  }
  out[((size_t)((b * H + hbase + V - 1) * W + wc)) * 2 + ri] =
      finish_sim(ax, ay, cxy);
}

// z in {0,1}: r=2 batch z; z in {2,3}: r=4 batch z-2. No LDS, no barriers.
__global__ __launch_bounds__(256, 2)
void cca_planar(const float* __restrict__ zb, float* __restrict__ out) {
  const int z = blockIdx.z;
  if (z < 2) run<2, 8>(zb, out, z, 0);
  else       run<4, 8>(zb, out, z - 2, 1);
}

extern "C" void kernel_launch(void* const* d_in, const int* in_sizes, int n_in,
                              void* d_out, int out_size, void* d_ws, size_t ws_size,
                              hipStream_t stream) {
  const float* x = (const float*)d_in[0];
  const float* y = (const float*)d_in[1];
  float* out = (float*)d_out;
  float* zb  = (float*)d_ws;   // needs 3*PSTR*4 B = 25.96 MB

  {
    const int n = 3 * 2 * HB * (HB / 4);   // 405,600 threads, 1585 blocks
    prep_planar_t<<<dim3((n + 255) / 256), dim3(256), 0, stream>>>(x, y, zb);
  }
  dim3 grid(512 / 16, 512 / (16 * 8), 4);   // 32 x 4 x 4 = 512 blocks
  cca_planar<<<grid, dim3(256), 0, stream>>>(zb, out);
}